// Round 6
// baseline (375.140 us; speedup 1.0000x reference)
//
#include <hip/hip_runtime.h>
#include <stdint.h>

// LocallyConnected1d: out[b,c,o] = (1/8) * sum_{i<64,k<8} x[b,i,4o+k] * w[c,i,o,k]
// B=128, CIN=64, COUT=64, OUT_DIM=256, K=8, S=4, L=1028. fp32 in/out.
//
// R9: single fused kernel with in-kernel producer->consumer handshake.
// Rationale: R4-R8 could not be attributed (both kernels < 41us profile
// cutoff, fillBuffer poison floods top-5). One kernel = one profile row.
// Structure:
//  phase W: each of 1024 blocks transposes a (4c x 16i x 16o) w chunk via LDS
//           (coalesced read 512B/row, coalesced write 1KB/wave) into wb
//           [q][ch][o_lo][c][i_loc][k] bf16, then threadfence + flag (release).
//  phase G: R8's verified flat GEMM: A (x-window) staged once full-K into
//           40KB LDS (ASTR=20), one barrier, wave-spin (acquire) on the 64
//           producer flags of its q-octet, then 16 unrolled K-steps reading
//           B fragments straight from wb (1KB/wave line-coalesced, L2-hot).
//  Deadlock-safe: spin times out -> fallback gathers B direct from w (slow
//  but correct), so co-residency is an optimization, not a requirement.

#define CIN_  64
#define COUT_ 64
#define OD_   256
#define K_    8
#define L_    1028

// wb granule layout: [q 128][ch 4][o_lo 2][c 64][i_loc 16] x (8 bf16 = 16B)
#define WB_PER_Q  65536
#define WB_PER_CH 16384

#define ASTR 20          // A_lds row stride in bf16 elems (40B, non-pow2)
#define MAGIC 0x5CA1AB1Eu
#define SPIN_LIMIT 200000

typedef __attribute__((ext_vector_type(8))) short bf16x8;
typedef __attribute__((ext_vector_type(4))) short short4v;
typedef __attribute__((ext_vector_type(4))) float floatx4;

__device__ __forceinline__ unsigned short f32_to_bf16(float f) {
    union { float f; uint32_t u; } v; v.f = f;
    uint32_t u = v.u;
    u += 0x7FFFu + ((u >> 16) & 1u);   // round-to-nearest-even
    return (unsigned short)(u >> 16);
}

__global__ __launch_bounds__(256, 4)
void lc1d_fused(const float* __restrict__ x,
                const float* __restrict__ w,
                float* __restrict__ out,
                unsigned short* wb,
                unsigned int* flags) {
    // LDS union: phase W uses first 17408 B as transpose tile (64 rows x 136
    // shorts); phase G uses all 40960 B as the A tile. Reuse separated by the
    // barrier after phase W's tile reads.
    __shared__ __align__(16) unsigned short lds[64 * 16 * ASTR];   // 40960 B

    const int tid = threadIdx.x;
    const int blk = blockIdx.x;

    // ================= phase W: w transpose chunk -> wb =================
    {
        const int c0 = (blk & 15) * 4;      // 16 c-tiles of 4
        const int ch = (blk >> 4) & 3;      // i-tile of 16
        const int i0 = ch * 16;
        const int ot = blk >> 6;            // 0..15 o-tile (16 o = 8 q)
        const int o0 = ot * 16;
        const int q0 = ot * 8;

        // read: 64 rows (cL*16+iL) x 512 B contiguous (16 o x 8 k floats)
        #pragma unroll
        for (int it = 0; it < 8; ++it) {
            const int u   = it * 256 + tid;
            const int t   = u & 31;         // float4 within row
            const int row = u >> 5;         // 0..63
            const int iL  = row & 15;
            const int cL  = row >> 4;       // 0..3
            const float4 v = *(const float4*)(w +
                (size_t)((c0 + cL) * CIN_ + (i0 + iL)) * (OD_ * K_) + o0 * K_ + t * 4);
            ushort4 sv = make_ushort4(f32_to_bf16(v.x), f32_to_bf16(v.y),
                                      f32_to_bf16(v.z), f32_to_bf16(v.w));
            *(ushort4*)&lds[row * 136 + t * 4] = sv;
        }
        __syncthreads();

        // write: granule (qL, o_lo, cL, il) -> 1 KB/wave contiguous in wb
        #pragma unroll
        for (int it = 0; it < 4; ++it) {
            const int u    = it * 256 + tid;
            const int il   = u & 15;
            const int cL   = (u >> 4) & 3;
            const int o_lo = (u >> 6) & 1;
            const int qL   = (u >> 7) & 7;
            const int row   = cL * 16 + il;
            const int o_loc = qL * 2 + o_lo;
            const bf16x8 vv = *(const bf16x8*)&lds[row * 136 + o_loc * 8];
            const size_t dst = (size_t)(q0 + qL) * WB_PER_Q + (size_t)ch * WB_PER_CH
                             + ((size_t)((o_lo * 64 + c0 + cL) * 16 + il) << 3);
            *(bf16x8*)&wb[dst] = vv;
        }
    }
    __threadfence();      // each thread: its wb stores visible device-wide
    __syncthreads();      // all threads fenced; also tile reads done pre-reuse
    if (tid == 0)
        __hip_atomic_store(&flags[blk], MAGIC, __ATOMIC_RELEASE,
                           __HIP_MEMORY_SCOPE_AGENT);

    // ================= phase G: GEMM (q, b-eighth) =================
    // XCD swizzle: XCD j hosts q in [16j,16j+16); blk,blk+128 -> same XCD
    const int q   = (blk & 7) * 16 + ((blk >> 3) & 15);
    const int bq  = blk >> 7;           // 0..7
    const int b0  = bq * 16;

    const int wave = tid >> 6;
    const int lane = tid & 63;
    const int quad = lane >> 4;
    const int l16  = lane & 15;
    const int o_lo = wave & 1;          // which o of the pair
    const int nth  = wave >> 1;         // c-half (c = nth*32 + n*16 + l16)

    // ---- A staging: rows (iL 0..63, bL 0..15) x 12 floats [8q, 8q+12) ----
    #pragma unroll
    for (int it = 0; it < 16; ++it) {
        const int u   = it * 256 + tid;
        const int t   = u & 3;          // float4 within row; t==3 masked
        const int row = u >> 2;         // 0..1023
        const int bL  = row & 15;
        const int iL  = row >> 4;       // 0..63
        if (t < 3) {
            const float4 v = *(const float4*)(x +
                (size_t)((b0 + bL) * CIN_ + iL) * L_ + q * 8 + t * 4);
            ushort4 sv = make_ushort4(f32_to_bf16(v.x), f32_to_bf16(v.y),
                                      f32_to_bf16(v.z), f32_to_bf16(v.w));
            *(ushort4*)&lds[(iL * 16 + bL) * ASTR + t * 4] = sv;
        }
    }
    __syncthreads();

    // ---- wave-spin (acquire) on the 64 producers of this q's octet ----
    const unsigned int* fp = flags + ((q >> 3) << 6);
    bool ok = true;
    {
        int iter = 0;
        for (;;) {
            const unsigned int fv = __hip_atomic_load(&fp[lane], __ATOMIC_ACQUIRE,
                                                      __HIP_MEMORY_SCOPE_AGENT);
            if (__ballot(fv != MAGIC) == 0ULL) break;
            if (++iter > SPIN_LIMIT) { ok = false; break; }   // fallback path
            __builtin_amdgcn_s_sleep(2);
        }
    }

    floatx4 acc[2];
    acc[0] = (floatx4){0.f, 0.f, 0.f, 0.f};
    acc[1] = (floatx4){0.f, 0.f, 0.f, 0.f};
    const int o_g = q * 2 + o_lo;

    if (ok) {
        // lane-constant part of wb ushort index:
        // q*65536 + [(o_lo*64 + nth*32 + n*16 + l16)*16 + (kt&3)*4+quad]*8
        const size_t wbase = (size_t)q * WB_PER_Q
                           + ((size_t)(o_lo * 64 + nth * 32 + l16) << 7) + (quad << 3);
        #pragma unroll 4
        for (int kt = 0; kt < 16; ++kt) {
            const int abase = ((kt * 4 + quad) * 16 + l16) * ASTR + o_lo * 4;
            const short4v a_lo = *(const short4v*)&lds[abase];
            const short4v a_hi = *(const short4v*)&lds[abase + 4];
            bf16x8 af;
            af[0] = a_lo[0]; af[1] = a_lo[1]; af[2] = a_lo[2]; af[3] = a_lo[3];
            af[4] = a_hi[0]; af[5] = a_hi[1]; af[6] = a_hi[2]; af[7] = a_hi[3];
            const size_t kbase = wbase + (size_t)(kt >> 2) * WB_PER_CH + ((kt & 3) << 5);
            #pragma unroll
            for (int n = 0; n < 2; ++n) {
                // wave load = 64x16B granules covering 16 full 64B lines
                const bf16x8 bf = *(const bf16x8*)&wb[kbase + (size_t)(n << 11)];
                acc[n] = __builtin_amdgcn_mfma_f32_16x16x32_bf16(af, bf, acc[n], 0, 0, 0);
            }
        }
    } else {
        // timeout fallback: gather B direct from w (correct, slower)
        #pragma unroll 4
        for (int kt = 0; kt < 16; ++kt) {
            const int i = kt * 4 + quad;
            const int abase = (i * 16 + l16) * ASTR + o_lo * 4;
            const short4v a_lo = *(const short4v*)&lds[abase];
            const short4v a_hi = *(const short4v*)&lds[abase + 4];
            bf16x8 af;
            af[0] = a_lo[0]; af[1] = a_lo[1]; af[2] = a_lo[2]; af[3] = a_lo[3];
            af[4] = a_hi[0]; af[5] = a_hi[1]; af[6] = a_hi[2]; af[7] = a_hi[3];
            #pragma unroll
            for (int n = 0; n < 2; ++n) {
                const int c = nth * 32 + n * 16 + l16;
                const float4* p = (const float4*)(w +
                    ((size_t)((c * CIN_ + i) * OD_ + o_g) << 3));
                const float4 v0 = p[0];
                const float4 v1 = p[1];
                bf16x8 bf;
                bf[0] = f32_to_bf16(v0.x); bf[1] = f32_to_bf16(v0.y);
                bf[2] = f32_to_bf16(v0.z); bf[3] = f32_to_bf16(v0.w);
                bf[4] = f32_to_bf16(v1.x); bf[5] = f32_to_bf16(v1.y);
                bf[6] = f32_to_bf16(v1.z); bf[7] = f32_to_bf16(v1.w);
                acc[n] = __builtin_amdgcn_mfma_f32_16x16x32_bf16(af, bf, acc[n], 0, 0, 0);
            }
        }
    }

    // ---- epilogue: D col=l16 (c), row=quad*4+reg (b); scale 1/sqrt(64) ----
    #pragma unroll
    for (int n = 0; n < 2; ++n) {
        const int c = nth * 32 + n * 16 + l16;
        #pragma unroll
        for (int r = 0; r < 4; ++r) {
            const int b = b0 + quad * 4 + r;
            out[((size_t)b * COUT_ + c) * OD_ + o_g] = acc[n][r] * 0.125f;
        }
    }
}

extern "C" void kernel_launch(void* const* d_in, const int* in_sizes, int n_in,
                              void* d_out, int out_size, void* d_ws, size_t ws_size,
                              hipStream_t stream) {
    const float* x = (const float*)d_in[0];   // (128, 64, 1028)
    const float* w = (const float*)d_in[1];   // (1, 64, 64, 256, 8)
    float* out = (float*)d_out;               // (128, 64, 256)
    unsigned short* wb = (unsigned short*)d_ws;                   // 16 MiB
    unsigned int* flags = (unsigned int*)((char*)d_ws + (16u << 20)); // +16 MiB

    hipLaunchKernelGGL(lc1d_fused, dim3(1024), dim3(256), 0, stream,
                       x, w, out, wb, flags);
}

// Round 7
// 121.733 us; speedup vs baseline: 3.0817x; 3.0817x over previous
//
#include <hip/hip_runtime.h>
#include <stdint.h>

// LocallyConnected1d: out[b,c,o] = (1/8) * sum_{i<64,k<8} x[b,i,4o+k] * w[c,i,o,k]
// B=128, CIN=64, COUT=64, OUT_DIM=256, K=8, S=4, L=1028. fp32 in/out.
//
// R10 = R4 (best verified, e2e 117.6, kernels ~44us) with occupancy raised.
// R9 post-mortem: in-kernel handshake = 325us (spin acquire-loads thrash
// caches). Reverted to two-launch. R4-vs-R8 ledger: DMA-B-into-LDS chunked
// K2 beats flat per-lane-B K2 by ~9us; R4 K2's only flaw was grid 512 ->
// 2 blocks/CU. Changes here, ONLY occupancy:
//  K1: R9's phase-W split (grid 1024, 4c x 16i x 16o per block, 4+ blk/CU),
//      same coalesced read/write, XOR baked as in R4.
//  K2: b-tile 32 -> 16 (Al 20 -> 10 KB, total LDS 42 KB -> 3 blk/CU,
//      12 waves/CU), grid 1024 (q 128 x bq 8), waves = (o_lo, c-half),
//      acc[2]. DMA B-staging, 4-chunk loop, fragment math: R4 verbatim.

#define CIN_  64
#define COUT_ 64
#define OD_   256
#define K_    8
#define L_    1028

// wb layout: [q 128][ch 4][o_lo 2][c 64][gs 16][k 8] bf16, gs = i_loc ^ (c&7)
#define WB_PER_Q  65536
#define WB_PER_CH 16384

#define ASTR 20   // A_lds row stride in bf16 elems (40 B: non-pow2 -> <=2-way banks)

typedef __attribute__((ext_vector_type(8))) short bf16x8;
typedef __attribute__((ext_vector_type(4))) short short4v;
typedef __attribute__((ext_vector_type(4))) float floatx4;

__device__ __forceinline__ unsigned short f32_to_bf16(float f) {
    union { float f; uint32_t u; } v; v.f = f;
    uint32_t u = v.u;
    u += 0x7FFFu + ((u >> 16) & 1u);   // round-to-nearest-even
    return (unsigned short)(u >> 16);
}

// ---------------- K1: w fp32 -> wb bf16 (transpose + swizzle) ----------------
// grid 1024 = 16 c-tiles(4) x 4 i-tiles(16) x 16 o-tiles(16). 256 threads.
__global__ __launch_bounds__(256, 4)
void lc1d_wprep(const float* __restrict__ w, unsigned short* __restrict__ wb) {
    __shared__ __align__(16) unsigned short tile[64 * 136];  // (c,i) rows x (16o x 8k), pad 8

    const int tid = threadIdx.x;
    const int blk = blockIdx.x;
    const int c0  = (blk & 15) * 4;
    const int ch  = (blk >> 4) & 3;
    const int i0  = ch * 16;
    const int ot  = blk >> 6;           // 0..15
    const int o0  = ot * 16;
    const int q0  = ot * 8;

    // read: 64 rows (cL*16+iL) x 512 B contiguous (16 o x 8 k floats)
    #pragma unroll
    for (int it = 0; it < 8; ++it) {
        const int u   = it * 256 + tid;
        const int t   = u & 31;         // float4 within row
        const int row = u >> 5;         // 0..63
        const int iL  = row & 15;
        const int cL  = row >> 4;       // 0..3
        const float4 v = *(const float4*)(w +
            (size_t)((c0 + cL) * CIN_ + (i0 + iL)) * (OD_ * K_) + o0 * K_ + t * 4);
        ushort4 sv = make_ushort4(f32_to_bf16(v.x), f32_to_bf16(v.y),
                                  f32_to_bf16(v.z), f32_to_bf16(v.w));
        *(ushort4*)&tile[row * 136 + t * 4] = sv;
    }
    __syncthreads();

    // write: granule (qL, o_lo, cL, gs) -> contiguous 16 B stores in wb order
    #pragma unroll
    for (int it = 0; it < 4; ++it) {
        const int u    = it * 256 + tid;
        const int gs   = u & 15;
        const int cL   = (u >> 4) & 3;
        const int o_lo = (u >> 6) & 1;
        const int qL   = (u >> 7) & 7;
        const int c    = c0 + cL;
        const int iL   = gs ^ (c & 7);  // bank-XOR baked into stored position
        const int row  = cL * 16 + iL;
        const int o_loc = qL * 2 + o_lo;
        const bf16x8 vv = *(const bf16x8*)&tile[row * 136 + o_loc * 8];
        const size_t dst = (size_t)(q0 + qL) * WB_PER_Q + (size_t)ch * WB_PER_CH
                         + ((size_t)((o_lo * 64 + c) * 16 + gs) << 3);
        *(bf16x8*)&wb[dst] = vv;
    }
}

// ---------------- K2: GEMM. block = (q, b-eighth), grid 1024 ----------------
__global__ __launch_bounds__(256, 3)
void lc1d_gemm(const float* __restrict__ x,
               const unsigned short* __restrict__ wb,
               float* __restrict__ out) {
    __shared__ __align__(16) unsigned short Bl[16384];           // 32 KB, flat = wb chunk
    __shared__ __align__(16) unsigned short Al[16 * 16 * ASTR];  // 10 KB

    const int tid = threadIdx.x;
    const int blk = blockIdx.x;
    // XCD swizzle: XCD j hosts q in [16j,16j+16); blk,blk+128 -> same XCD
    const int q   = (blk & 7) * 16 + ((blk >> 3) & 15);
    const int bq  = blk >> 7;           // 0..7
    const int b0  = bq * 16;

    const int wave = tid >> 6;
    const int lane = tid & 63;
    const int quad = lane >> 4;
    const int l16  = lane & 15;
    const int o_lo = wave & 1;          // which o of the pair
    const int nth  = wave >> 1;         // c-half (c = nth*32 + n*16 + l16)

    floatx4 acc[2];
    acc[0] = (floatx4){0.f, 0.f, 0.f, 0.f};
    acc[1] = (floatx4){0.f, 0.f, 0.f, 0.f};

    for (int ch = 0; ch < 4; ++ch) {
        // ---- w staging: flat async copy wb[q][ch] -> Bl (32 KB), zero VALU ----
        const char* wsrc = (const char*)(wb + (size_t)q * WB_PER_Q + (size_t)ch * WB_PER_CH);
        #pragma unroll
        for (int j = 0; j < 8; ++j) {
            const int off = wave * 8192 + j * 1024;
            auto gp = (const __attribute__((address_space(1))) uint32_t*)(wsrc + off + lane * 16);
            auto lp = (__attribute__((address_space(3))) uint32_t*)((char*)&Bl[0] + off);
            __builtin_amdgcn_global_load_lds(gp, lp, 16, 0, 0);
        }

        // ---- x staging: rows (iL 0..15, bL 0..15) x 12 floats [8q, 8q+12) ----
        #pragma unroll
        for (int it = 0; it < 4; ++it) {
            const int u   = it * 256 + tid;
            const int t   = u & 3;          // float4 within row; t==3 masked
            const int row = u >> 2;         // 0..255
            const int bL  = row & 15;
            const int iL  = row >> 4;       // 0..15
            if (t < 3) {
                const float4 v = *(const float4*)(x +
                    (size_t)((b0 + bL) * CIN_ + ch * 16 + iL) * L_ + q * 8 + t * 4);
                ushort4 sv = make_ushort4(f32_to_bf16(v.x), f32_to_bf16(v.y),
                                          f32_to_bf16(v.z), f32_to_bf16(v.w));
                *(ushort4*)&Al[(iL * 16 + bL) * ASTR + t * 4] = sv;
            }
        }
        __syncthreads();   // drains vmcnt (DMA) + lgkm (LDS stores)

        // ---- compute: 4 k-steps of 32 (i_loc = kt*4+quad, k = 0..7) ----
        #pragma unroll
        for (int kt = 0; kt < 4; ++kt) {
            const int i_l   = kt * 4 + quad;
            const int abase = (i_l * 16 + l16) * ASTR + o_lo * 4;
            const short4v a_lo = *(const short4v*)&Al[abase];
            const short4v a_hi = *(const short4v*)&Al[abase + 4];
            bf16x8 af;
            af[0] = a_lo[0]; af[1] = a_lo[1]; af[2] = a_lo[2]; af[3] = a_lo[3];
            af[4] = a_hi[0]; af[5] = a_hi[1]; af[6] = a_hi[2]; af[7] = a_hi[3];
            #pragma unroll
            for (int n = 0; n < 2; ++n) {
                const int c  = nth * 32 + n * 16 + l16;
                const int gs = i_l ^ (c & 7);
                const bf16x8 bf = *(const bf16x8*)&Bl[((o_lo * 64 + c) * 16 + gs) << 3];
                acc[n] = __builtin_amdgcn_mfma_f32_16x16x32_bf16(af, bf, acc[n], 0, 0, 0);
            }
        }
        __syncthreads();   // LDS reads done before next chunk overwrites
    }

    // ---- epilogue: D col=l16 (c), row=quad*4+reg (b); scale 1/sqrt(64) ----
    const int o_g = q * 2 + o_lo;
    #pragma unroll
    for (int n = 0; n < 2; ++n) {
        const int c = nth * 32 + n * 16 + l16;
        #pragma unroll
        for (int r = 0; r < 4; ++r) {
            const int b = b0 + quad * 4 + r;
            out[((size_t)b * COUT_ + c) * OD_ + o_g] = acc[n][r] * 0.125f;
        }
    }
}

extern "C" void kernel_launch(void* const* d_in, const int* in_sizes, int n_in,
                              void* d_out, int out_size, void* d_ws, size_t ws_size,
                              hipStream_t stream) {
    const float* x = (const float*)d_in[0];   // (128, 64, 1028)
    const float* w = (const float*)d_in[1];   // (1, 64, 64, 256, 8)
    float* out = (float*)d_out;               // (128, 64, 256)
    unsigned short* wb = (unsigned short*)d_ws; // 16 MiB bf16 workspace

    hipLaunchKernelGGL(lc1d_wprep, dim3(1024), dim3(256), 0, stream, w, wb);
    hipLaunchKernelGGL(lc1d_gemm,  dim3(1024), dim3(256), 0, stream, x, wb, out);
}